// Round 15
// baseline (437.938 us; speedup 1.0000x reference)
//
#include <hip/hip_runtime.h>
#include <hip/hip_bf16.h>

#define NB 256      // batch
#define D 64        // embedding dim
#define NI 10000    // items

typedef __attribute__((ext_vector_type(8))) short bf16x8;
typedef __attribute__((ext_vector_type(16))) float f32x16;

union PK8 { unsigned u[4]; bf16x8 v; };
union F16Q { f32x16 v; float4 q[4]; };

// ws layout (float offsets)
static constexpr int WS_AL  = 0;                  // A_l [256][32]
static constexpr int WS_AR  = 8192;               // A_r [256][32]
static constexpr int WS_N   = 16384;              // n   [256][64]
static constexpr int WS_CL  = 32768;              // C_l [10000][32]
static constexpr int WS_CR  = 352768;             // C_r [10000][32]
static constexpr int WS_TAB = 672768;             // packed weight tables, 2 x 4608 floats
// table per head (4608 floats = 18 groups of [64 lanes][4 words], 16B units):
//   g0..g5   = w1a,w1b,w2a,w2b,w3a,w3b  (PK8 fragment words, u32)
//   g6..g9   = binit1[0..15] (f32) | g10..g13 = binit2 | g14..g17 = b3 splat

// out layout (elements, f32)
static constexpr long OUT_LIKES = 0;
static constexpr long OUT_SIM   = 2560000;
static constexpr long OUT_RATED = 2625536;
static constexpr long OUT_POP   = 5185536;

// Inline-asm packed cvt (R14 A/B result: plain casts are NOT fused by clang
// and cost +30% time; the single v_cvt_pk_bf16_f32 is the efficient form here)
__device__ __forceinline__ unsigned pkbf(float a, float b) {
    unsigned r;
    asm("v_cvt_pk_bf16_f32 %0, %1, %2" : "=v"(r) : "v"(a), "v"(b));
    return r;
}
__device__ __forceinline__ float relu(float x) { return fmaxf(x, 0.f); }

struct A4 { float4 a0, a1, a2, a3; };
__device__ __forceinline__ A4 ldA(const float* p) {
    A4 r;
    r.a0 = *(const float4*)p;        r.a1 = *(const float4*)(p + 4);
    r.a2 = *(const float4*)(p + 16); r.a3 = *(const float4*)(p + 20);
    return r;
}

// ================= prep: weight-table builder | popular-head (MFMA) | item C-proj | users
__global__ __launch_bounds__(256) void k_prep(
        const int* __restrict__ users, const float* __restrict__ uemb,
        const float* __restrict__ iemb,
        const float* __restrict__ lw0, const float* __restrict__ lb0,
        const float* __restrict__ rw0, const float* __restrict__ rb0,
        const float* __restrict__ lw1, const float* __restrict__ lb1,
        const float* __restrict__ lw2, const float* __restrict__ lb2,
        const float* __restrict__ lw3, const float* __restrict__ lb3,
        const float* __restrict__ rw1, const float* __restrict__ rb1,
        const float* __restrict__ rw2, const float* __restrict__ rb2,
        const float* __restrict__ rw3, const float* __restrict__ rb3,
        const float* __restrict__ pw0, const float* __restrict__ pb0,
        const float* __restrict__ pw1, const float* __restrict__ pb1,
        const float* __restrict__ pw2, const float* __restrict__ pb2,
        const float* __restrict__ pw3, const float* __restrict__ pb3,
        float* __restrict__ ws, float* __restrict__ out) {
    int bx = blockIdx.x, t = threadIdx.x;
    if (bx == 0) {
        // ---- build per-lane packed fragment tables for both pair heads
        if (t >= 128) return;
        int head = t >> 6, lane = t & 63;
        int pr = lane & 31, hi = lane >> 5;
        const float* W1 = head ? rw1 : lw1; const float* B1 = head ? rb1 : lb1;
        const float* W2 = head ? rw2 : lw2; const float* B2 = head ? rb2 : lb2;
        const float* w3 = head ? rw3 : lw3; const float* b3 = head ? rb3 : lb3;
        PK8 w1a, w1b, w2a, w2b, w3a, w3b;
        #pragma unroll
        for (int j = 0; j < 4; ++j) {
            int k0 = 8 * hi + 2 * j;
            w1a.u[j] = pkbf(W1[k0 * 32 + pr],        W1[(k0 + 1) * 32 + pr]);
            w1b.u[j] = pkbf(W1[(16 + k0) * 32 + pr], W1[(17 + k0) * 32 + pr]);
            int fa = ((2 * j) & 3) + 8 * ((2 * j) >> 2) + 4 * hi;
            int fb = ((2 * j + 1) & 3) + 8 * ((2 * j + 1) >> 2) + 4 * hi;
            w2a.u[j] = pkbf(W2[fa * 32 + pr],        W2[fb * 32 + pr]);
            w2b.u[j] = pkbf(W2[(fa + 16) * 32 + pr], W2[(fb + 16) * 32 + pr]);
            w3a.u[j] = pkbf(w3[fa],                  w3[fb]);
            w3b.u[j] = pkbf(w3[fa + 16],             w3[fb + 16]);
        }
        float* base = ws + WS_TAB + head * 4608;
        ((uint4*)base)[0 * 64 + lane] = *(uint4*)&w1a;
        ((uint4*)base)[1 * 64 + lane] = *(uint4*)&w1b;
        ((uint4*)base)[2 * 64 + lane] = *(uint4*)&w2a;
        ((uint4*)base)[3 * 64 + lane] = *(uint4*)&w2b;
        ((uint4*)base)[4 * 64 + lane] = *(uint4*)&w3a;
        ((uint4*)base)[5 * 64 + lane] = *(uint4*)&w3b;
        #pragma unroll
        for (int q = 0; q < 4; ++q) {
            float4 v1, v2;
            #pragma unroll
            for (int e = 0; e < 4; ++e) {
                int r = 4 * q + e;
                int f = (r & 3) + 8 * (r >> 2) + 4 * hi;
                ((float*)&v1)[e] = B1[f];
                ((float*)&v2)[e] = B2[f];
            }
            ((float4*)base)[(6 + q) * 64 + lane]  = v1;
            ((float4*)base)[(10 + q) * 64 + lane] = v2;
        }
        float b3v = b3[0];
        float4 bs; bs.x = b3v; bs.y = b3v; bs.z = b3v; bs.w = b3v;
        #pragma unroll
        for (int q = 0; q < 4; ++q) ((float4*)base)[(14 + q) * 64 + lane] = bs;
    } else if (bx < 80) {
        // ---- popular = item_head(item_emb) on MFMA: one wave = 32 items
        int wv = t >> 6, lane = t & 63;
        int w = (bx - 1) * 4 + wv;
        if (w >= 313) return;
        int i0 = w * 32;
        int pr = lane & 31, hi = lane >> 5;
        int crow = i0 + pr; if (crow > NI - 1) crow = NI - 1;
        const float4* xr = (const float4*)(iemb + (long)crow * D);
        PK8 xm[4], w0f[4];
        #pragma unroll
        for (int m = 0; m < 4; ++m) {
            float4 xa = xr[4 * m + 2 * hi];
            float4 xb = xr[4 * m + 2 * hi + 1];
            xm[m].u[0] = pkbf(xa.x, xa.y); xm[m].u[1] = pkbf(xa.z, xa.w);
            xm[m].u[2] = pkbf(xb.x, xb.y); xm[m].u[3] = pkbf(xb.z, xb.w);
            #pragma unroll
            for (int j = 0; j < 4; ++j) {
                int r0 = 16 * m + 8 * hi + 2 * j;
                w0f[m].u[j] = pkbf(pw0[r0 * 32 + pr], pw0[(r0 + 1) * 32 + pr]);
            }
        }
        PK8 w1a, w1b, w2a, w2b, w3a, w3b;
        f32x16 b0i, b1i, b2i, b3i;
        #pragma unroll
        for (int j = 0; j < 4; ++j) {
            int fa = ((2 * j) & 3) + 8 * ((2 * j) >> 2) + 4 * hi;
            int fb = ((2 * j + 1) & 3) + 8 * ((2 * j + 1) >> 2) + 4 * hi;
            w1a.u[j] = pkbf(pw1[fa * 32 + pr],        pw1[fb * 32 + pr]);
            w1b.u[j] = pkbf(pw1[(fa + 16) * 32 + pr], pw1[(fb + 16) * 32 + pr]);
            w2a.u[j] = pkbf(pw2[fa * 32 + pr],        pw2[fb * 32 + pr]);
            w2b.u[j] = pkbf(pw2[(fa + 16) * 32 + pr], pw2[(fb + 16) * 32 + pr]);
            w3a.u[j] = pkbf(pw3[fa],                  pw3[fb]);
            w3b.u[j] = pkbf(pw3[fa + 16],             pw3[fb + 16]);
        }
        float b3s = pb3[0];
        #pragma unroll
        for (int r = 0; r < 16; ++r) {
            int f = (r & 3) + 8 * (r >> 2) + 4 * hi;
            b0i[r] = pb0[f]; b1i[r] = pb1[f]; b2i[r] = pb2[f]; b3i[r] = b3s;
        }
        f32x16 acc;
        acc = __builtin_amdgcn_mfma_f32_32x32x16_bf16(w0f[0].v, xm[0].v, b0i, 0, 0, 0);
        acc = __builtin_amdgcn_mfma_f32_32x32x16_bf16(w0f[1].v, xm[1].v, acc, 0, 0, 0);
        acc = __builtin_amdgcn_mfma_f32_32x32x16_bf16(w0f[2].v, xm[2].v, acc, 0, 0, 0);
        acc = __builtin_amdgcn_mfma_f32_32x32x16_bf16(w0f[3].v, xm[3].v, acc, 0, 0, 0);
        PK8 g0, g1;
        #pragma unroll
        for (int j = 0; j < 4; ++j) {
            g0.u[j] = pkbf(relu(acc[2 * j]),     relu(acc[2 * j + 1]));
            g1.u[j] = pkbf(relu(acc[8 + 2 * j]), relu(acc[9 + 2 * j]));
        }
        f32x16 a1;
        a1 = __builtin_amdgcn_mfma_f32_32x32x16_bf16(w1a.v, g0.v, b1i, 0, 0, 0);
        a1 = __builtin_amdgcn_mfma_f32_32x32x16_bf16(w1b.v, g1.v, a1, 0, 0, 0);
        #pragma unroll
        for (int j = 0; j < 4; ++j) {
            g0.u[j] = pkbf(relu(a1[2 * j]),     relu(a1[2 * j + 1]));
            g1.u[j] = pkbf(relu(a1[8 + 2 * j]), relu(a1[9 + 2 * j]));
        }
        f32x16 a2;
        a2 = __builtin_amdgcn_mfma_f32_32x32x16_bf16(w2a.v, g0.v, b2i, 0, 0, 0);
        a2 = __builtin_amdgcn_mfma_f32_32x32x16_bf16(w2b.v, g1.v, a2, 0, 0, 0);
        #pragma unroll
        for (int j = 0; j < 4; ++j) {
            g0.u[j] = pkbf(relu(a2[2 * j]),     relu(a2[2 * j + 1]));
            g1.u[j] = pkbf(relu(a2[8 + 2 * j]), relu(a2[9 + 2 * j]));
        }
        f32x16 a3;
        a3 = __builtin_amdgcn_mfma_f32_32x32x16_bf16(w3a.v, g0.v, b3i, 0, 0, 0);
        a3 = __builtin_amdgcn_mfma_f32_32x32x16_bf16(w3b.v, g1.v, a3, 0, 0, 0);
        float o = 1.f / (1.f + __expf(-a3[0]));
        if (hi == 0 && i0 + pr < NI) out[OUT_POP + i0 + pr] = o;
    } else if (bx < 80 + 1250) {
        // ---- item projections C = ie @ W0[D:] for both heads
        int i0 = (bx - 80) * 8;
        __shared__ float xs[8][D];
        for (int idx = t; idx < 8 * D; idx += 256) {
            int it = idx >> 6, d = idx & 63; int gi = i0 + it;
            xs[it][d] = (gi < NI) ? iemb[(long)gi * D + d] : 0.f;
        }
        __syncthreads();
        int it = t >> 5, j = t & 31; int gi = i0 + it;
        float al = 0.f, ar = 0.f;
        #pragma unroll
        for (int d = 0; d < D; ++d) {
            float x = xs[it][d];
            al += x * lw0[(D + d) * 32 + j];
            ar += x * rw0[(D + d) * 32 + j];
        }
        if (gi < NI) { ws[WS_CL + gi * 32 + j] = al; ws[WS_CR + gi * 32 + j] = ar; }
    } else {
        // ---- user precompute: 4 users per block, one wave each
        __shared__ float es[4][D];
        int ug = t >> 6, tt = t & 63;
        int b = (bx - 1330) * 4 + ug;
        int u = users[b];
        float e = uemb[(long)u * D + tt];
        float s = e * e;
        #pragma unroll
        for (int off = 32; off; off >>= 1) s += __shfl_down(s, off);
        s = __shfl(s, 0);
        ws[WS_N + b * D + tt] = e * rsqrtf(fmaxf(s, 1e-12f));
        es[ug][tt] = e;
        __syncthreads();
        const float* W0 = (tt < 32) ? lw0 : rw0;
        const float* bb = (tt < 32) ? lb0 : rb0;
        int j = tt & 31;
        float acc = bb[j];
        #pragma unroll
        for (int d = 0; d < D; ++d) acc += es[ug][d] * W0[d * 32 + j];
        ws[((tt < 32) ? WS_AL : WS_AR) + b * 32 + j] = acc;
    }
}

// ================= main: MFMA pair heads (likes+rated) + user_sim
// R15 = R13 loop (asm pkbf restored — R14 A/B proved it faster) but packaged
// as 128-thread blocks holding TWO fully independent waves (no LDS, no
// barrier). CDNA caps ~16 workgroups/CU: 64-thread blocks capped residency at
// 16 waves/CU (50%); 2 waves/block doubles the reachable pool to 32 waves/CU
// (VGPR=60 <= 64 allows 8 waves/SIMD).
__global__ __launch_bounds__(128, 8) void k_main(
        const float* __restrict__ ws, float* __restrict__ out) {
    int wave = threadIdx.x >> 6, lane = threadIdx.x & 63;
    int unit = blockIdx.x * 2 + wave;           // virtual 1-wave block id
    if (unit < 10016) {
        int head = unit & 1;
        int ug = (unit >> 1) & 15;
        int ib = unit >> 5;                 // [0, 313)
        int i0 = ib * 32;
        int a_off = head ? WS_AR : WS_AL;
        int c_off = head ? WS_CR : WS_CL;
        float* ob = out + (head ? OUT_RATED : OUT_LIKES);

        int pr = lane & 31, hi = lane >> 5;
        int u0 = ug * 16;

        // ---- fragments + persistent bias C-ins straight from the global table
        const uint4*  tu = (const uint4*)(ws + WS_TAB + head * 4608);
        const float4* tq = (const float4*)(ws + WS_TAB + head * 4608);
        PK8 w1a, w1b, w2a, w2b, w3a, w3b;
        *(uint4*)&w1a = tu[0 * 64 + lane];
        *(uint4*)&w1b = tu[1 * 64 + lane];
        *(uint4*)&w2a = tu[2 * 64 + lane];
        *(uint4*)&w2b = tu[3 * 64 + lane];
        *(uint4*)&w3a = tu[4 * 64 + lane];
        *(uint4*)&w3b = tu[5 * 64 + lane];
        F16Q bin1, bin2, bin3;
        bin1.q[0] = tq[6 * 64 + lane];  bin1.q[1] = tq[7 * 64 + lane];
        bin1.q[2] = tq[8 * 64 + lane];  bin1.q[3] = tq[9 * 64 + lane];
        bin2.q[0] = tq[10 * 64 + lane]; bin2.q[1] = tq[11 * 64 + lane];
        bin2.q[2] = tq[12 * 64 + lane]; bin2.q[3] = tq[13 * 64 + lane];
        bin3.q[0] = tq[14 * 64 + lane]; bin3.q[1] = tq[15 * 64 + lane];
        bin3.q[2] = tq[16 * 64 + lane]; bin3.q[3] = tq[17 * 64 + lane];

        // ---- item projection values (fixed per unit): C[pr][k] in kappa1 slots
        int crow = i0 + pr; if (crow > NI - 1) crow = NI - 1;
        const float* cp = ws + c_off + (long)crow * 32 + 8 * hi;
        float4 c0 = *(const float4*)cp;
        float4 c1 = *(const float4*)(cp + 4);
        float4 c2 = *(const float4*)(cp + 16);
        float4 c3 = *(const float4*)(cp + 20);

        bool valid = (hi == 0) && (i0 + pr < NI);
        float* op = ob + (long)u0 * NI + i0 + pr;
        const float* ap = ws + a_off + 8 * hi + (long)u0 * 32;

        for (int u = 0; u < 16; ++u) {
            A4 a = ldA(ap + (long)u * 32);
            // ---- X fragment (float4 adds -> v_pk_add_f32)
            float4 s0 = a.a0 + c0, s1 = a.a1 + c1, s2 = a.a2 + c2, s3 = a.a3 + c3;
            PK8 x0, x1;
            x0.u[0] = pkbf(relu(s0.x), relu(s0.y));
            x0.u[1] = pkbf(relu(s0.z), relu(s0.w));
            x0.u[2] = pkbf(relu(s1.x), relu(s1.y));
            x0.u[3] = pkbf(relu(s1.z), relu(s1.w));
            x1.u[0] = pkbf(relu(s2.x), relu(s2.y));
            x1.u[1] = pkbf(relu(s2.z), relu(s2.w));
            x1.u[2] = pkbf(relu(s3.x), relu(s3.y));
            x1.u[3] = pkbf(relu(s3.z), relu(s3.w));
            // ---- layer 1 (persistent bin1 as C; D != C)
            F16Q acc;
            acc.v = __builtin_amdgcn_mfma_f32_32x32x16_bf16(w1a.v, x0.v, bin1.v, 0, 0, 0);
            acc.v = __builtin_amdgcn_mfma_f32_32x32x16_bf16(w1b.v, x1.v, acc.v, 0, 0, 0);
            // ---- relu+pack, layer 2
            PK8 h0, h1;
            #pragma unroll
            for (int j = 0; j < 4; ++j) {
                h0.u[j] = pkbf(relu(acc.v[2 * j]),     relu(acc.v[2 * j + 1]));
                h1.u[j] = pkbf(relu(acc.v[8 + 2 * j]), relu(acc.v[9 + 2 * j]));
            }
            F16Q acc2;
            acc2.v = __builtin_amdgcn_mfma_f32_32x32x16_bf16(w2a.v, h0.v, bin2.v, 0, 0, 0);
            acc2.v = __builtin_amdgcn_mfma_f32_32x32x16_bf16(w2b.v, h1.v, acc2.v, 0, 0, 0);
            // ---- relu+pack, layer-3 dot on MFMA (C-in = persistent b3 splat)
            PK8 g0, g1;
            #pragma unroll
            for (int j = 0; j < 4; ++j) {
                g0.u[j] = pkbf(relu(acc2.v[2 * j]),     relu(acc2.v[2 * j + 1]));
                g1.u[j] = pkbf(relu(acc2.v[8 + 2 * j]), relu(acc2.v[9 + 2 * j]));
            }
            F16Q acc3;
            acc3.v = __builtin_amdgcn_mfma_f32_32x32x16_bf16(w3a.v, g0.v, bin3.v, 0, 0, 0);
            acc3.v = __builtin_amdgcn_mfma_f32_32x32x16_bf16(w3b.v, g1.v, acc3.v, 0, 0, 0);
            // ---- sigmoid + store
            float o = 1.f / (1.f + __expf(-acc3.v[0]));
            if (valid) *op = o;
            op += NI;
        }
    } else if (unit < 10016 + 1024) {
        // ---- user_sim: one 64-lane unit per (b, 64-col group)
        int bs = unit - 10016;
        int b = bs >> 2, j = (bs & 3) * 64 + lane;
        const float4* nb = (const float4*)(ws + WS_N + b * D);   // wave-uniform
        const float4* nj = (const float4*)(ws + WS_N + j * D);
        float acc = 0.f;
        #pragma unroll
        for (int d4 = 0; d4 < 16; ++d4) {
            float4 u = nb[d4];
            float4 v = nj[d4];
            acc += u.x * v.x + u.y * v.y + u.z * v.z + u.w * v.w;
        }
        out[OUT_SIM + (long)b * 256 + j] = (1.f - acc) * 0.5f;
    }
}

extern "C" void kernel_launch(void* const* d_in, const int* in_sizes, int n_in,
                              void* d_out, int out_size, void* d_ws, size_t ws_size,
                              hipStream_t stream) {
    const int*   users = (const int*)d_in[0];
    const float* uemb  = (const float*)d_in[1];
    const float* iemb  = (const float*)d_in[2];
    const float *lw0 = (const float*)d_in[3],  *lb0 = (const float*)d_in[4];
    const float *lw1 = (const float*)d_in[5],  *lb1 = (const float*)d_in[6];
    const float *lw2 = (const float*)d_in[7],  *lb2 = (const float*)d_in[8];
    const float *lw3 = (const float*)d_in[9],  *lb3 = (const float*)d_in[10];
    const float *rw0 = (const float*)d_in[11], *rb0 = (const float*)d_in[12];
    const float *rw1 = (const float*)d_in[13], *rb1 = (const float*)d_in[14];
    const float *rw2 = (const float*)d_in[15], *rb2 = (const float*)d_in[16];
    const float *rw3 = (const float*)d_in[17], *rb3 = (const float*)d_in[18];
    const float *pw0 = (const float*)d_in[19], *pb0 = (const float*)d_in[20];
    const float *pw1 = (const float*)d_in[21], *pb1 = (const float*)d_in[22];
    const float *pw2 = (const float*)d_in[23], *pb2 = (const float*)d_in[24];
    const float *pw3 = (const float*)d_in[25], *pb3 = (const float*)d_in[26];
    float* ws = (float*)d_ws;
    float* out = (float*)d_out;

    k_prep<<<1394, 256, 0, stream>>>(users, uemb, iemb,
                                     lw0, lb0, rw0, rb0,
                                     lw1, lb1, lw2, lb2, lw3, lb3,
                                     rw1, rb1, rw2, rb2, rw3, rb3,
                                     pw0, pb0, pw1, pb1, pw2, pb2, pw3, pb3,
                                     ws, out);
    // (10016 + 1024) units / 2 waves per block = 5520 blocks
    k_main<<<5520, 128, 0, stream>>>(ws, out);
}

// Round 16
// 70.102 us; speedup vs baseline: 6.2472x; 6.2472x over previous
//
#include <hip/hip_runtime.h>
#include <hip/hip_bf16.h>

#define NB 256      // batch
#define D 64        // embedding dim
#define NI 10000    // items

typedef __attribute__((ext_vector_type(8))) short bf16x8;
typedef __attribute__((ext_vector_type(16))) float f32x16;

union PK8 { unsigned u[4]; bf16x8 v; };
union F16Q { f32x16 v; float4 q[4]; };

// ws layout (float offsets)
static constexpr int WS_AL  = 0;                  // A_l [256][32]
static constexpr int WS_AR  = 8192;               // A_r [256][32]
static constexpr int WS_N   = 16384;              // n   [256][64]
static constexpr int WS_CL  = 32768;              // C_l [10000][32]
static constexpr int WS_CR  = 352768;             // C_r [10000][32]
static constexpr int WS_TAB = 672768;             // packed weight tables, 2 x 4608 floats
// table per head (4608 floats = 18 groups of [64 lanes][4 words], 16B units):
//   g0..g5   = w1a,w1b,w2a,w2b,w3a,w3b  (PK8 fragment words, u32)
//   g6..g9   = binit1[0..15] (f32) | g10..g13 = binit2 | g14..g17 = b3 splat

// out layout (elements, f32)
static constexpr long OUT_LIKES = 0;
static constexpr long OUT_SIM   = 2560000;
static constexpr long OUT_RATED = 2625536;
static constexpr long OUT_POP   = 5185536;

// Inline-asm packed cvt (R14 A/B: plain casts are NOT fused by clang, +30% time)
__device__ __forceinline__ unsigned pkbf(float a, float b) {
    unsigned r;
    asm("v_cvt_pk_bf16_f32 %0, %1, %2" : "=v"(r) : "v"(a), "v"(b));
    return r;
}
__device__ __forceinline__ float relu(float x) { return fmaxf(x, 0.f); }

struct A4 { float4 a0, a1, a2, a3; };
__device__ __forceinline__ A4 ldA(const float* p) {
    A4 r;
    r.a0 = *(const float4*)p;        r.a1 = *(const float4*)(p + 4);
    r.a2 = *(const float4*)(p + 16); r.a3 = *(const float4*)(p + 20);
    return r;
}

// ================= prep: weight-table builder | popular-head (MFMA) | item C-proj | users
__global__ __launch_bounds__(256) void k_prep(
        const int* __restrict__ users, const float* __restrict__ uemb,
        const float* __restrict__ iemb,
        const float* __restrict__ lw0, const float* __restrict__ lb0,
        const float* __restrict__ rw0, const float* __restrict__ rb0,
        const float* __restrict__ lw1, const float* __restrict__ lb1,
        const float* __restrict__ lw2, const float* __restrict__ lb2,
        const float* __restrict__ lw3, const float* __restrict__ lb3,
        const float* __restrict__ rw1, const float* __restrict__ rb1,
        const float* __restrict__ rw2, const float* __restrict__ rb2,
        const float* __restrict__ rw3, const float* __restrict__ rb3,
        const float* __restrict__ pw0, const float* __restrict__ pb0,
        const float* __restrict__ pw1, const float* __restrict__ pb1,
        const float* __restrict__ pw2, const float* __restrict__ pb2,
        const float* __restrict__ pw3, const float* __restrict__ pb3,
        float* __restrict__ ws, float* __restrict__ out) {
    int bx = blockIdx.x, t = threadIdx.x;
    if (bx == 0) {
        // ---- build per-lane packed fragment tables for both pair heads
        if (t >= 128) return;
        int head = t >> 6, lane = t & 63;
        int pr = lane & 31, hi = lane >> 5;
        const float* W1 = head ? rw1 : lw1; const float* B1 = head ? rb1 : lb1;
        const float* W2 = head ? rw2 : lw2; const float* B2 = head ? rb2 : lb2;
        const float* w3 = head ? rw3 : lw3; const float* b3 = head ? rb3 : lb3;
        PK8 w1a, w1b, w2a, w2b, w3a, w3b;
        #pragma unroll
        for (int j = 0; j < 4; ++j) {
            int k0 = 8 * hi + 2 * j;
            w1a.u[j] = pkbf(W1[k0 * 32 + pr],        W1[(k0 + 1) * 32 + pr]);
            w1b.u[j] = pkbf(W1[(16 + k0) * 32 + pr], W1[(17 + k0) * 32 + pr]);
            int fa = ((2 * j) & 3) + 8 * ((2 * j) >> 2) + 4 * hi;
            int fb = ((2 * j + 1) & 3) + 8 * ((2 * j + 1) >> 2) + 4 * hi;
            w2a.u[j] = pkbf(W2[fa * 32 + pr],        W2[fb * 32 + pr]);
            w2b.u[j] = pkbf(W2[(fa + 16) * 32 + pr], W2[(fb + 16) * 32 + pr]);
            w3a.u[j] = pkbf(w3[fa],                  w3[fb]);
            w3b.u[j] = pkbf(w3[fa + 16],             w3[fb + 16]);
        }
        float* base = ws + WS_TAB + head * 4608;
        ((uint4*)base)[0 * 64 + lane] = *(uint4*)&w1a;
        ((uint4*)base)[1 * 64 + lane] = *(uint4*)&w1b;
        ((uint4*)base)[2 * 64 + lane] = *(uint4*)&w2a;
        ((uint4*)base)[3 * 64 + lane] = *(uint4*)&w2b;
        ((uint4*)base)[4 * 64 + lane] = *(uint4*)&w3a;
        ((uint4*)base)[5 * 64 + lane] = *(uint4*)&w3b;
        #pragma unroll
        for (int q = 0; q < 4; ++q) {
            float4 v1, v2;
            #pragma unroll
            for (int e = 0; e < 4; ++e) {
                int r = 4 * q + e;
                int f = (r & 3) + 8 * (r >> 2) + 4 * hi;
                ((float*)&v1)[e] = B1[f];
                ((float*)&v2)[e] = B2[f];
            }
            ((float4*)base)[(6 + q) * 64 + lane]  = v1;
            ((float4*)base)[(10 + q) * 64 + lane] = v2;
        }
        float b3v = b3[0];
        float4 bs; bs.x = b3v; bs.y = b3v; bs.z = b3v; bs.w = b3v;
        #pragma unroll
        for (int q = 0; q < 4; ++q) ((float4*)base)[(14 + q) * 64 + lane] = bs;
    } else if (bx < 80) {
        // ---- popular = item_head(item_emb) on MFMA: one wave = 32 items
        int wv = t >> 6, lane = t & 63;
        int w = (bx - 1) * 4 + wv;
        if (w >= 313) return;
        int i0 = w * 32;
        int pr = lane & 31, hi = lane >> 5;
        int crow = i0 + pr; if (crow > NI - 1) crow = NI - 1;
        const float4* xr = (const float4*)(iemb + (long)crow * D);
        PK8 xm[4], w0f[4];
        #pragma unroll
        for (int m = 0; m < 4; ++m) {
            float4 xa = xr[4 * m + 2 * hi];
            float4 xb = xr[4 * m + 2 * hi + 1];
            xm[m].u[0] = pkbf(xa.x, xa.y); xm[m].u[1] = pkbf(xa.z, xa.w);
            xm[m].u[2] = pkbf(xb.x, xb.y); xm[m].u[3] = pkbf(xb.z, xb.w);
            #pragma unroll
            for (int j = 0; j < 4; ++j) {
                int r0 = 16 * m + 8 * hi + 2 * j;
                w0f[m].u[j] = pkbf(pw0[r0 * 32 + pr], pw0[(r0 + 1) * 32 + pr]);
            }
        }
        PK8 w1a, w1b, w2a, w2b, w3a, w3b;
        f32x16 b0i, b1i, b2i, b3i;
        #pragma unroll
        for (int j = 0; j < 4; ++j) {
            int fa = ((2 * j) & 3) + 8 * ((2 * j) >> 2) + 4 * hi;
            int fb = ((2 * j + 1) & 3) + 8 * ((2 * j + 1) >> 2) + 4 * hi;
            w1a.u[j] = pkbf(pw1[fa * 32 + pr],        pw1[fb * 32 + pr]);
            w1b.u[j] = pkbf(pw1[(fa + 16) * 32 + pr], pw1[(fb + 16) * 32 + pr]);
            w2a.u[j] = pkbf(pw2[fa * 32 + pr],        pw2[fb * 32 + pr]);
            w2b.u[j] = pkbf(pw2[(fa + 16) * 32 + pr], pw2[(fb + 16) * 32 + pr]);
            w3a.u[j] = pkbf(pw3[fa],                  pw3[fb]);
            w3b.u[j] = pkbf(pw3[fa + 16],             pw3[fb + 16]);
        }
        float b3s = pb3[0];
        #pragma unroll
        for (int r = 0; r < 16; ++r) {
            int f = (r & 3) + 8 * (r >> 2) + 4 * hi;
            b0i[r] = pb0[f]; b1i[r] = pb1[f]; b2i[r] = pb2[f]; b3i[r] = b3s;
        }
        f32x16 acc;
        acc = __builtin_amdgcn_mfma_f32_32x32x16_bf16(w0f[0].v, xm[0].v, b0i, 0, 0, 0);
        acc = __builtin_amdgcn_mfma_f32_32x32x16_bf16(w0f[1].v, xm[1].v, acc, 0, 0, 0);
        acc = __builtin_amdgcn_mfma_f32_32x32x16_bf16(w0f[2].v, xm[2].v, acc, 0, 0, 0);
        acc = __builtin_amdgcn_mfma_f32_32x32x16_bf16(w0f[3].v, xm[3].v, acc, 0, 0, 0);
        PK8 g0, g1;
        #pragma unroll
        for (int j = 0; j < 4; ++j) {
            g0.u[j] = pkbf(relu(acc[2 * j]),     relu(acc[2 * j + 1]));
            g1.u[j] = pkbf(relu(acc[8 + 2 * j]), relu(acc[9 + 2 * j]));
        }
        f32x16 a1;
        a1 = __builtin_amdgcn_mfma_f32_32x32x16_bf16(w1a.v, g0.v, b1i, 0, 0, 0);
        a1 = __builtin_amdgcn_mfma_f32_32x32x16_bf16(w1b.v, g1.v, a1, 0, 0, 0);
        #pragma unroll
        for (int j = 0; j < 4; ++j) {
            g0.u[j] = pkbf(relu(a1[2 * j]),     relu(a1[2 * j + 1]));
            g1.u[j] = pkbf(relu(a1[8 + 2 * j]), relu(a1[9 + 2 * j]));
        }
        f32x16 a2;
        a2 = __builtin_amdgcn_mfma_f32_32x32x16_bf16(w2a.v, g0.v, b2i, 0, 0, 0);
        a2 = __builtin_amdgcn_mfma_f32_32x32x16_bf16(w2b.v, g1.v, a2, 0, 0, 0);
        #pragma unroll
        for (int j = 0; j < 4; ++j) {
            g0.u[j] = pkbf(relu(a2[2 * j]),     relu(a2[2 * j + 1]));
            g1.u[j] = pkbf(relu(a2[8 + 2 * j]), relu(a2[9 + 2 * j]));
        }
        f32x16 a3;
        a3 = __builtin_amdgcn_mfma_f32_32x32x16_bf16(w3a.v, g0.v, b3i, 0, 0, 0);
        a3 = __builtin_amdgcn_mfma_f32_32x32x16_bf16(w3b.v, g1.v, a3, 0, 0, 0);
        float o = 1.f / (1.f + __expf(-a3[0]));
        if (hi == 0 && i0 + pr < NI) out[OUT_POP + i0 + pr] = o;
    } else if (bx < 80 + 1250) {
        // ---- item projections C = ie @ W0[D:] for both heads
        int i0 = (bx - 80) * 8;
        __shared__ float xs[8][D];
        for (int idx = t; idx < 8 * D; idx += 256) {
            int it = idx >> 6, d = idx & 63; int gi = i0 + it;
            xs[it][d] = (gi < NI) ? iemb[(long)gi * D + d] : 0.f;
        }
        __syncthreads();
        int it = t >> 5, j = t & 31; int gi = i0 + it;
        float al = 0.f, ar = 0.f;
        #pragma unroll
        for (int d = 0; d < D; ++d) {
            float x = xs[it][d];
            al += x * lw0[(D + d) * 32 + j];
            ar += x * rw0[(D + d) * 32 + j];
        }
        if (gi < NI) { ws[WS_CL + gi * 32 + j] = al; ws[WS_CR + gi * 32 + j] = ar; }
    } else {
        // ---- user precompute: 4 users per block, one wave each
        __shared__ float es[4][D];
        int ug = t >> 6, tt = t & 63;
        int b = (bx - 1330) * 4 + ug;
        int u = users[b];
        float e = uemb[(long)u * D + tt];
        float s = e * e;
        #pragma unroll
        for (int off = 32; off; off >>= 1) s += __shfl_down(s, off);
        s = __shfl(s, 0);
        ws[WS_N + b * D + tt] = e * rsqrtf(fmaxf(s, 1e-12f));
        es[ug][tt] = e;
        __syncthreads();
        const float* W0 = (tt < 32) ? lw0 : rw0;
        const float* bb = (tt < 32) ? lb0 : rb0;
        int j = tt & 31;
        float acc = bb[j];
        #pragma unroll
        for (int d = 0; d < D; ++d) acc += es[ug][d] * W0[d * 32 + j];
        ws[((tt < 32) ? WS_AL : WS_AR) + b * 32 + j] = acc;
    }
}

// ================= main: MFMA pair heads (likes+rated) + user_sim
// R16 = R15 structure (2 independent waves / 128-thread block, no LDS, no
// barrier; beats the 16-workgroup/CU cap that limited R13 to 16 waves/CU)
// with a NON-BINDING register bound: __launch_bounds__(128,4) -> 128-VGPR
// budget, no spill (R15's (128,8) forced 64 -> VGPR_Count=32 + 1.37 GB of
// scratch traffic, 7x regression). Actual residency: VGPR~60 -> 8 waves/SIMD.
__global__ __launch_bounds__(128, 4) void k_main(
        const float* __restrict__ ws, float* __restrict__ out) {
    int wave = threadIdx.x >> 6, lane = threadIdx.x & 63;
    int unit = blockIdx.x * 2 + wave;           // virtual 1-wave block id
    if (unit < 10016) {
        int head = unit & 1;
        int ug = (unit >> 1) & 15;
        int ib = unit >> 5;                 // [0, 313)
        int i0 = ib * 32;
        int a_off = head ? WS_AR : WS_AL;
        int c_off = head ? WS_CR : WS_CL;
        float* ob = out + (head ? OUT_RATED : OUT_LIKES);

        int pr = lane & 31, hi = lane >> 5;
        int u0 = ug * 16;

        // ---- fragments + persistent bias C-ins straight from the global table
        const uint4*  tu = (const uint4*)(ws + WS_TAB + head * 4608);
        const float4* tq = (const float4*)(ws + WS_TAB + head * 4608);
        PK8 w1a, w1b, w2a, w2b, w3a, w3b;
        *(uint4*)&w1a = tu[0 * 64 + lane];
        *(uint4*)&w1b = tu[1 * 64 + lane];
        *(uint4*)&w2a = tu[2 * 64 + lane];
        *(uint4*)&w2b = tu[3 * 64 + lane];
        *(uint4*)&w3a = tu[4 * 64 + lane];
        *(uint4*)&w3b = tu[5 * 64 + lane];
        F16Q bin1, bin2, bin3;
        bin1.q[0] = tq[6 * 64 + lane];  bin1.q[1] = tq[7 * 64 + lane];
        bin1.q[2] = tq[8 * 64 + lane];  bin1.q[3] = tq[9 * 64 + lane];
        bin2.q[0] = tq[10 * 64 + lane]; bin2.q[1] = tq[11 * 64 + lane];
        bin2.q[2] = tq[12 * 64 + lane]; bin2.q[3] = tq[13 * 64 + lane];
        bin3.q[0] = tq[14 * 64 + lane]; bin3.q[1] = tq[15 * 64 + lane];
        bin3.q[2] = tq[16 * 64 + lane]; bin3.q[3] = tq[17 * 64 + lane];

        // ---- item projection values (fixed per unit): C[pr][k] in kappa1 slots
        int crow = i0 + pr; if (crow > NI - 1) crow = NI - 1;
        const float* cp = ws + c_off + (long)crow * 32 + 8 * hi;
        float4 c0 = *(const float4*)cp;
        float4 c1 = *(const float4*)(cp + 4);
        float4 c2 = *(const float4*)(cp + 16);
        float4 c3 = *(const float4*)(cp + 20);

        bool valid = (hi == 0) && (i0 + pr < NI);
        float* op = ob + (long)u0 * NI + i0 + pr;
        const float* ap = ws + a_off + 8 * hi + (long)u0 * 32;

        for (int u = 0; u < 16; ++u) {
            A4 a = ldA(ap + (long)u * 32);
            // ---- X fragment (float4 adds -> v_pk_add_f32)
            float4 s0 = a.a0 + c0, s1 = a.a1 + c1, s2 = a.a2 + c2, s3 = a.a3 + c3;
            PK8 x0, x1;
            x0.u[0] = pkbf(relu(s0.x), relu(s0.y));
            x0.u[1] = pkbf(relu(s0.z), relu(s0.w));
            x0.u[2] = pkbf(relu(s1.x), relu(s1.y));
            x0.u[3] = pkbf(relu(s1.z), relu(s1.w));
            x1.u[0] = pkbf(relu(s2.x), relu(s2.y));
            x1.u[1] = pkbf(relu(s2.z), relu(s2.w));
            x1.u[2] = pkbf(relu(s3.x), relu(s3.y));
            x1.u[3] = pkbf(relu(s3.z), relu(s3.w));
            // ---- layer 1 (persistent bin1 as C; D != C)
            F16Q acc;
            acc.v = __builtin_amdgcn_mfma_f32_32x32x16_bf16(w1a.v, x0.v, bin1.v, 0, 0, 0);
            acc.v = __builtin_amdgcn_mfma_f32_32x32x16_bf16(w1b.v, x1.v, acc.v, 0, 0, 0);
            // ---- relu+pack, layer 2
            PK8 h0, h1;
            #pragma unroll
            for (int j = 0; j < 4; ++j) {
                h0.u[j] = pkbf(relu(acc.v[2 * j]),     relu(acc.v[2 * j + 1]));
                h1.u[j] = pkbf(relu(acc.v[8 + 2 * j]), relu(acc.v[9 + 2 * j]));
            }
            F16Q acc2;
            acc2.v = __builtin_amdgcn_mfma_f32_32x32x16_bf16(w2a.v, h0.v, bin2.v, 0, 0, 0);
            acc2.v = __builtin_amdgcn_mfma_f32_32x32x16_bf16(w2b.v, h1.v, acc2.v, 0, 0, 0);
            // ---- relu+pack, layer-3 dot on MFMA (C-in = persistent b3 splat)
            PK8 g0, g1;
            #pragma unroll
            for (int j = 0; j < 4; ++j) {
                g0.u[j] = pkbf(relu(acc2.v[2 * j]),     relu(acc2.v[2 * j + 1]));
                g1.u[j] = pkbf(relu(acc2.v[8 + 2 * j]), relu(acc2.v[9 + 2 * j]));
            }
            F16Q acc3;
            acc3.v = __builtin_amdgcn_mfma_f32_32x32x16_bf16(w3a.v, g0.v, bin3.v, 0, 0, 0);
            acc3.v = __builtin_amdgcn_mfma_f32_32x32x16_bf16(w3b.v, g1.v, acc3.v, 0, 0, 0);
            // ---- sigmoid + store
            float o = 1.f / (1.f + __expf(-acc3.v[0]));
            if (valid) *op = o;
            op += NI;
        }
    } else if (unit < 10016 + 1024) {
        // ---- user_sim: one 64-lane unit per (b, 64-col group)
        int bs = unit - 10016;
        int b = bs >> 2, j = (bs & 3) * 64 + lane;
        const float4* nb = (const float4*)(ws + WS_N + b * D);   // wave-uniform
        const float4* nj = (const float4*)(ws + WS_N + j * D);
        float acc = 0.f;
        #pragma unroll
        for (int d4 = 0; d4 < 16; ++d4) {
            float4 u = nb[d4];
            float4 v = nj[d4];
            acc += u.x * v.x + u.y * v.y + u.z * v.z + u.w * v.w;
        }
        out[OUT_SIM + (long)b * 256 + j] = (1.f - acc) * 0.5f;
    }
}

extern "C" void kernel_launch(void* const* d_in, const int* in_sizes, int n_in,
                              void* d_out, int out_size, void* d_ws, size_t ws_size,
                              hipStream_t stream) {
    const int*   users = (const int*)d_in[0];
    const float* uemb  = (const float*)d_in[1];
    const float* iemb  = (const float*)d_in[2];
    const float *lw0 = (const float*)d_in[3],  *lb0 = (const float*)d_in[4];
    const float *lw1 = (const float*)d_in[5],  *lb1 = (const float*)d_in[6];
    const float *lw2 = (const float*)d_in[7],  *lb2 = (const float*)d_in[8];
    const float *lw3 = (const float*)d_in[9],  *lb3 = (const float*)d_in[10];
    const float *rw0 = (const float*)d_in[11], *rb0 = (const float*)d_in[12];
    const float *rw1 = (const float*)d_in[13], *rb1 = (const float*)d_in[14];
    const float *rw2 = (const float*)d_in[15], *rb2 = (const float*)d_in[16];
    const float *rw3 = (const float*)d_in[17], *rb3 = (const float*)d_in[18];
    const float *pw0 = (const float*)d_in[19], *pb0 = (const float*)d_in[20];
    const float *pw1 = (const float*)d_in[21], *pb1 = (const float*)d_in[22];
    const float *pw2 = (const float*)d_in[23], *pb2 = (const float*)d_in[24];
    const float *pw3 = (const float*)d_in[25], *pb3 = (const float*)d_in[26];
    float* ws = (float*)d_ws;
    float* out = (float*)d_out;

    k_prep<<<1394, 256, 0, stream>>>(users, uemb, iemb,
                                     lw0, lb0, rw0, rb0,
                                     lw1, lb1, lw2, lb2, lw3, lb3,
                                     rw1, rb1, rw2, rb2, rw3, rb3,
                                     pw0, pb0, pw1, pb1, pw2, pb2, pw3, pb3,
                                     ws, out);
    // (10016 + 1024) units / 2 waves per block = 5520 blocks
    k_main<<<5520, 128, 0, stream>>>(ws, out);
}

// Round 17
// 65.696 us; speedup vs baseline: 6.6662x; 1.0671x over previous
//
#include <hip/hip_runtime.h>
#include <hip/hip_bf16.h>

#define NB 256      // batch
#define D 64        // embedding dim
#define NI 10000    // items

typedef __attribute__((ext_vector_type(8))) short bf16x8;
typedef __attribute__((ext_vector_type(16))) float f32x16;

union PK8 { unsigned u[4]; bf16x8 v; };
union F16Q { f32x16 v; float4 q[4]; };

// ws layout (float offsets)
static constexpr int WS_AL  = 0;                  // A_l [256][32]
static constexpr int WS_AR  = 8192;               // A_r [256][32]
static constexpr int WS_N   = 16384;              // n   [256][64]
static constexpr int WS_CL  = 32768;              // C_l [10000][32]
static constexpr int WS_CR  = 352768;             // C_r [10000][32]
static constexpr int WS_TAB = 672768;             // packed weight tables, 2 x 4608 floats
// table per head (4608 floats = 18 groups of [64 lanes][4 words], 16B units):
//   g0..g5   = w1a,w1b,w2a,w2b,w3a,w3b  (PK8 fragment words, u32)
//   g6..g9   = binit1[0..15] (f32) | g10..g13 = binit2 | g14..g17 = b3 splat

// out layout (elements, f32)
static constexpr long OUT_LIKES = 0;
static constexpr long OUT_SIM   = 2560000;
static constexpr long OUT_RATED = 2625536;
static constexpr long OUT_POP   = 5185536;

// 2 f32 -> packed 2x bf16 (RNE). R14 A/B: plain casts are NOT fused by clang
// (+30% time); the single-instruction asm form is the efficient one here.
__device__ __forceinline__ unsigned pkbf(float a, float b) {
    unsigned r;
    asm("v_cvt_pk_bf16_f32 %0, %1, %2" : "=v"(r) : "v"(a), "v"(b));
    return r;
}
__device__ __forceinline__ float relu(float x) { return fmaxf(x, 0.f); }

struct A4 { float4 a0, a1, a2, a3; };
__device__ __forceinline__ A4 ldA(const float* p) {
    A4 r;
    r.a0 = *(const float4*)p;        r.a1 = *(const float4*)(p + 4);
    r.a2 = *(const float4*)(p + 16); r.a3 = *(const float4*)(p + 20);
    return r;
}

// ================= prep: weight-table builder | popular-head (MFMA) | item C-proj | users
__global__ __launch_bounds__(256) void k_prep(
        const int* __restrict__ users, const float* __restrict__ uemb,
        const float* __restrict__ iemb,
        const float* __restrict__ lw0, const float* __restrict__ lb0,
        const float* __restrict__ rw0, const float* __restrict__ rb0,
        const float* __restrict__ lw1, const float* __restrict__ lb1,
        const float* __restrict__ lw2, const float* __restrict__ lb2,
        const float* __restrict__ lw3, const float* __restrict__ lb3,
        const float* __restrict__ rw1, const float* __restrict__ rb1,
        const float* __restrict__ rw2, const float* __restrict__ rb2,
        const float* __restrict__ rw3, const float* __restrict__ rb3,
        const float* __restrict__ pw0, const float* __restrict__ pb0,
        const float* __restrict__ pw1, const float* __restrict__ pb1,
        const float* __restrict__ pw2, const float* __restrict__ pb2,
        const float* __restrict__ pw3, const float* __restrict__ pb3,
        float* __restrict__ ws, float* __restrict__ out) {
    int bx = blockIdx.x, t = threadIdx.x;
    if (bx == 0) {
        // ---- build per-lane packed fragment tables for both pair heads
        if (t >= 128) return;
        int head = t >> 6, lane = t & 63;
        int pr = lane & 31, hi = lane >> 5;
        const float* W1 = head ? rw1 : lw1; const float* B1 = head ? rb1 : lb1;
        const float* W2 = head ? rw2 : lw2; const float* B2 = head ? rb2 : lb2;
        const float* w3 = head ? rw3 : lw3; const float* b3 = head ? rb3 : lb3;
        PK8 w1a, w1b, w2a, w2b, w3a, w3b;
        #pragma unroll
        for (int j = 0; j < 4; ++j) {
            int k0 = 8 * hi + 2 * j;
            w1a.u[j] = pkbf(W1[k0 * 32 + pr],        W1[(k0 + 1) * 32 + pr]);
            w1b.u[j] = pkbf(W1[(16 + k0) * 32 + pr], W1[(17 + k0) * 32 + pr]);
            int fa = ((2 * j) & 3) + 8 * ((2 * j) >> 2) + 4 * hi;
            int fb = ((2 * j + 1) & 3) + 8 * ((2 * j + 1) >> 2) + 4 * hi;
            w2a.u[j] = pkbf(W2[fa * 32 + pr],        W2[fb * 32 + pr]);
            w2b.u[j] = pkbf(W2[(fa + 16) * 32 + pr], W2[(fb + 16) * 32 + pr]);
            w3a.u[j] = pkbf(w3[fa],                  w3[fb]);
            w3b.u[j] = pkbf(w3[fa + 16],             w3[fb + 16]);
        }
        float* base = ws + WS_TAB + head * 4608;
        ((uint4*)base)[0 * 64 + lane] = *(uint4*)&w1a;
        ((uint4*)base)[1 * 64 + lane] = *(uint4*)&w1b;
        ((uint4*)base)[2 * 64 + lane] = *(uint4*)&w2a;
        ((uint4*)base)[3 * 64 + lane] = *(uint4*)&w2b;
        ((uint4*)base)[4 * 64 + lane] = *(uint4*)&w3a;
        ((uint4*)base)[5 * 64 + lane] = *(uint4*)&w3b;
        #pragma unroll
        for (int q = 0; q < 4; ++q) {
            float4 v1, v2;
            #pragma unroll
            for (int e = 0; e < 4; ++e) {
                int r = 4 * q + e;
                int f = (r & 3) + 8 * (r >> 2) + 4 * hi;
                ((float*)&v1)[e] = B1[f];
                ((float*)&v2)[e] = B2[f];
            }
            ((float4*)base)[(6 + q) * 64 + lane]  = v1;
            ((float4*)base)[(10 + q) * 64 + lane] = v2;
        }
        float b3v = b3[0];
        float4 bs; bs.x = b3v; bs.y = b3v; bs.z = b3v; bs.w = b3v;
        #pragma unroll
        for (int q = 0; q < 4; ++q) ((float4*)base)[(14 + q) * 64 + lane] = bs;
    } else if (bx < 80) {
        // ---- popular = item_head(item_emb) on MFMA: one wave = 32 items
        int wv = t >> 6, lane = t & 63;
        int w = (bx - 1) * 4 + wv;
        if (w >= 313) return;
        int i0 = w * 32;
        int pr = lane & 31, hi = lane >> 5;
        int crow = i0 + pr; if (crow > NI - 1) crow = NI - 1;
        const float4* xr = (const float4*)(iemb + (long)crow * D);
        PK8 xm[4], w0f[4];
        #pragma unroll
        for (int m = 0; m < 4; ++m) {
            float4 xa = xr[4 * m + 2 * hi];
            float4 xb = xr[4 * m + 2 * hi + 1];
            xm[m].u[0] = pkbf(xa.x, xa.y); xm[m].u[1] = pkbf(xa.z, xa.w);
            xm[m].u[2] = pkbf(xb.x, xb.y); xm[m].u[3] = pkbf(xb.z, xb.w);
            #pragma unroll
            for (int j = 0; j < 4; ++j) {
                int r0 = 16 * m + 8 * hi + 2 * j;
                w0f[m].u[j] = pkbf(pw0[r0 * 32 + pr], pw0[(r0 + 1) * 32 + pr]);
            }
        }
        PK8 w1a, w1b, w2a, w2b, w3a, w3b;
        f32x16 b0i, b1i, b2i, b3i;
        #pragma unroll
        for (int j = 0; j < 4; ++j) {
            int fa = ((2 * j) & 3) + 8 * ((2 * j) >> 2) + 4 * hi;
            int fb = ((2 * j + 1) & 3) + 8 * ((2 * j + 1) >> 2) + 4 * hi;
            w1a.u[j] = pkbf(pw1[fa * 32 + pr],        pw1[fb * 32 + pr]);
            w1b.u[j] = pkbf(pw1[(fa + 16) * 32 + pr], pw1[(fb + 16) * 32 + pr]);
            w2a.u[j] = pkbf(pw2[fa * 32 + pr],        pw2[fb * 32 + pr]);
            w2b.u[j] = pkbf(pw2[(fa + 16) * 32 + pr], pw2[(fb + 16) * 32 + pr]);
            w3a.u[j] = pkbf(pw3[fa],                  pw3[fb]);
            w3b.u[j] = pkbf(pw3[fa + 16],             pw3[fb + 16]);
        }
        float b3s = pb3[0];
        #pragma unroll
        for (int r = 0; r < 16; ++r) {
            int f = (r & 3) + 8 * (r >> 2) + 4 * hi;
            b0i[r] = pb0[f]; b1i[r] = pb1[f]; b2i[r] = pb2[f]; b3i[r] = b3s;
        }
        f32x16 acc = b0i;
        acc = __builtin_amdgcn_mfma_f32_32x32x16_bf16(w0f[0].v, xm[0].v, acc, 0, 0, 0);
        acc = __builtin_amdgcn_mfma_f32_32x32x16_bf16(w0f[1].v, xm[1].v, acc, 0, 0, 0);
        acc = __builtin_amdgcn_mfma_f32_32x32x16_bf16(w0f[2].v, xm[2].v, acc, 0, 0, 0);
        acc = __builtin_amdgcn_mfma_f32_32x32x16_bf16(w0f[3].v, xm[3].v, acc, 0, 0, 0);
        PK8 g0, g1;
        #pragma unroll
        for (int j = 0; j < 4; ++j) {
            g0.u[j] = pkbf(relu(acc[2 * j]),     relu(acc[2 * j + 1]));
            g1.u[j] = pkbf(relu(acc[8 + 2 * j]), relu(acc[9 + 2 * j]));
        }
        f32x16 a1 = b1i;
        a1 = __builtin_amdgcn_mfma_f32_32x32x16_bf16(w1a.v, g0.v, a1, 0, 0, 0);
        a1 = __builtin_amdgcn_mfma_f32_32x32x16_bf16(w1b.v, g1.v, a1, 0, 0, 0);
        #pragma unroll
        for (int j = 0; j < 4; ++j) {
            g0.u[j] = pkbf(relu(a1[2 * j]),     relu(a1[2 * j + 1]));
            g1.u[j] = pkbf(relu(a1[8 + 2 * j]), relu(a1[9 + 2 * j]));
        }
        f32x16 a2 = b2i;
        a2 = __builtin_amdgcn_mfma_f32_32x32x16_bf16(w2a.v, g0.v, a2, 0, 0, 0);
        a2 = __builtin_amdgcn_mfma_f32_32x32x16_bf16(w2b.v, g1.v, a2, 0, 0, 0);
        #pragma unroll
        for (int j = 0; j < 4; ++j) {
            g0.u[j] = pkbf(relu(a2[2 * j]),     relu(a2[2 * j + 1]));
            g1.u[j] = pkbf(relu(a2[8 + 2 * j]), relu(a2[9 + 2 * j]));
        }
        f32x16 a3 = b3i;
        a3 = __builtin_amdgcn_mfma_f32_32x32x16_bf16(w3a.v, g0.v, a3, 0, 0, 0);
        a3 = __builtin_amdgcn_mfma_f32_32x32x16_bf16(w3b.v, g1.v, a3, 0, 0, 0);
        float o = 1.f / (1.f + __expf(-a3[0]));
        if (hi == 0 && i0 + pr < NI) out[OUT_POP + i0 + pr] = o;
    } else if (bx < 80 + 1250) {
        // ---- item projections C = ie @ W0[D:] for both heads
        int i0 = (bx - 80) * 8;
        __shared__ float xs[8][D];
        for (int idx = t; idx < 8 * D; idx += 256) {
            int it = idx >> 6, d = idx & 63; int gi = i0 + it;
            xs[it][d] = (gi < NI) ? iemb[(long)gi * D + d] : 0.f;
        }
        __syncthreads();
        int it = t >> 5, j = t & 31; int gi = i0 + it;
        float al = 0.f, ar = 0.f;
        #pragma unroll
        for (int d = 0; d < D; ++d) {
            float x = xs[it][d];
            al += x * lw0[(D + d) * 32 + j];
            ar += x * rw0[(D + d) * 32 + j];
        }
        if (gi < NI) { ws[WS_CL + gi * 32 + j] = al; ws[WS_CR + gi * 32 + j] = ar; }
    } else {
        // ---- user precompute: 4 users per block, one wave each
        __shared__ float es[4][D];
        int ug = t >> 6, tt = t & 63;
        int b = (bx - 1330) * 4 + ug;
        int u = users[b];
        float e = uemb[(long)u * D + tt];
        float s = e * e;
        #pragma unroll
        for (int off = 32; off; off >>= 1) s += __shfl_down(s, off);
        s = __shfl(s, 0);
        ws[WS_N + b * D + tt] = e * rsqrtf(fmaxf(s, 1e-12f));
        es[ug][tt] = e;
        __syncthreads();
        const float* W0 = (tt < 32) ? lw0 : rw0;
        const float* bb = (tt < 32) ? lb0 : rb0;
        int j = tt & 31;
        float acc = bb[j];
        #pragma unroll
        for (int d = 0; d < D; ++d) acc += es[ug][d] * W0[d * 32 + j];
        ws[((tt < 32) ? WS_AL : WS_AR) + b * 32 + j] = acc;
    }
}

// ================= main: MFMA pair heads (likes+rated) + user_sim
// FINAL (R10 config — empirical best of 6 structural variants, 58.6 us k_main /
// 65.7 us total): 256-thread blocks, per-block LDS weight table, 2-user ILP
// loop, builtin MFMA with bias C-in read from LDS into acc unions, asm
// v_cvt_pk_bf16_f32 packs, __launch_bounds__(256,3).
__global__ __launch_bounds__(256, 3) void k_main(
        const float* __restrict__ ws, float* __restrict__ out) {
    __shared__ float tabf[4608];
    int bx = blockIdx.x, t = threadIdx.x;
    if (bx < 2504) {
        int head = bx & 1;
        int ug = (bx >> 1) & 3;
        int ib = bx >> 3;                 // [0, 313)
        int i0 = ib * 32;
        int a_off = head ? WS_AR : WS_AL;
        int c_off = head ? WS_CR : WS_CL;
        float* ob = out + (head ? OUT_RATED : OUT_LIKES);

        // ---- stage this head's table into LDS (1152 x float4, coalesced)
        {
            const float4* g = (const float4*)(ws + WS_TAB + head * 4608);
            float4* l = (float4*)tabf;
            for (int idx = t; idx < 1152; idx += 256) l[idx] = g[idx];
        }
        __syncthreads();

        int lane = t & 63, wv = t >> 6;
        int pr = lane & 31, hi = lane >> 5;
        int u0 = ug * 64 + wv * 16;

        const uint4*  tu = (const uint4*)tabf;
        const float4* tq = (const float4*)tabf;
        PK8 w1a, w1b, w2a, w2b, w3a, w3b;
        *(uint4*)&w1a = tu[0 * 64 + lane];
        *(uint4*)&w1b = tu[1 * 64 + lane];
        *(uint4*)&w2a = tu[2 * 64 + lane];
        *(uint4*)&w2b = tu[3 * 64 + lane];
        *(uint4*)&w3a = tu[4 * 64 + lane];
        *(uint4*)&w3b = tu[5 * 64 + lane];

        // ---- item projection values (fixed per block): C[pr][k] in kappa1 slots
        int crow = i0 + pr; if (crow > NI - 1) crow = NI - 1;
        const float* cp = ws + c_off + (long)crow * 32 + 8 * hi;
        float4 c0 = *(const float4*)cp;
        float4 c1 = *(const float4*)(cp + 4);
        float4 c2 = *(const float4*)(cp + 16);
        float4 c3 = *(const float4*)(cp + 20);

        bool valid = (hi == 0) && (i0 + pr < NI);
        float* op = ob + (long)u0 * NI + i0 + pr;
        const float* ap = ws + a_off + 8 * hi + (long)u0 * 32;

        for (int u = 0; u < 16; u += 2) {
            A4 aA = ldA(ap + (long)u * 32);
            A4 aB = ldA(ap + (long)(u + 1) * 32);
            // ---- X fragments, both users (independent chains)
            PK8 xA0, xA1, xB0, xB1;
            xA0.u[0] = pkbf(relu(aA.a0.x + c0.x), relu(aA.a0.y + c0.y));
            xA0.u[1] = pkbf(relu(aA.a0.z + c0.z), relu(aA.a0.w + c0.w));
            xA0.u[2] = pkbf(relu(aA.a1.x + c1.x), relu(aA.a1.y + c1.y));
            xA0.u[3] = pkbf(relu(aA.a1.z + c1.z), relu(aA.a1.w + c1.w));
            xA1.u[0] = pkbf(relu(aA.a2.x + c2.x), relu(aA.a2.y + c2.y));
            xA1.u[1] = pkbf(relu(aA.a2.z + c2.z), relu(aA.a2.w + c2.w));
            xA1.u[2] = pkbf(relu(aA.a3.x + c3.x), relu(aA.a3.y + c3.y));
            xA1.u[3] = pkbf(relu(aA.a3.z + c3.z), relu(aA.a3.w + c3.w));
            xB0.u[0] = pkbf(relu(aB.a0.x + c0.x), relu(aB.a0.y + c0.y));
            xB0.u[1] = pkbf(relu(aB.a0.z + c0.z), relu(aB.a0.w + c0.w));
            xB0.u[2] = pkbf(relu(aB.a1.x + c1.x), relu(aB.a1.y + c1.y));
            xB0.u[3] = pkbf(relu(aB.a1.z + c1.z), relu(aB.a1.w + c1.w));
            xB1.u[0] = pkbf(relu(aB.a2.x + c2.x), relu(aB.a2.y + c2.y));
            xB1.u[1] = pkbf(relu(aB.a2.z + c2.z), relu(aB.a2.w + c2.w));
            xB1.u[2] = pkbf(relu(aB.a3.x + c3.x), relu(aB.a3.y + c3.y));
            xB1.u[3] = pkbf(relu(aB.a3.z + c3.z), relu(aB.a3.w + c3.w));
            // ---- layer 1 (bias C-in from LDS; one read pair feeds both users)
            F16Q accA, accB;
            accA.q[0] = tq[6 * 64 + lane]; accA.q[1] = tq[7 * 64 + lane];
            accA.q[2] = tq[8 * 64 + lane]; accA.q[3] = tq[9 * 64 + lane];
            accB = accA;
            accA.v = __builtin_amdgcn_mfma_f32_32x32x16_bf16(w1a.v, xA0.v, accA.v, 0, 0, 0);
            accB.v = __builtin_amdgcn_mfma_f32_32x32x16_bf16(w1a.v, xB0.v, accB.v, 0, 0, 0);
            accA.v = __builtin_amdgcn_mfma_f32_32x32x16_bf16(w1b.v, xA1.v, accA.v, 0, 0, 0);
            accB.v = __builtin_amdgcn_mfma_f32_32x32x16_bf16(w1b.v, xB1.v, accB.v, 0, 0, 0);
            // ---- relu+pack, layer 2
            PK8 hA0, hA1, hB0, hB1;
            #pragma unroll
            for (int j = 0; j < 4; ++j) {
                hA0.u[j] = pkbf(relu(accA.v[2 * j]),     relu(accA.v[2 * j + 1]));
                hA1.u[j] = pkbf(relu(accA.v[8 + 2 * j]), relu(accA.v[9 + 2 * j]));
                hB0.u[j] = pkbf(relu(accB.v[2 * j]),     relu(accB.v[2 * j + 1]));
                hB1.u[j] = pkbf(relu(accB.v[8 + 2 * j]), relu(accB.v[9 + 2 * j]));
            }
            F16Q acc2A, acc2B;
            acc2A.q[0] = tq[10 * 64 + lane]; acc2A.q[1] = tq[11 * 64 + lane];
            acc2A.q[2] = tq[12 * 64 + lane]; acc2A.q[3] = tq[13 * 64 + lane];
            acc2B = acc2A;
            acc2A.v = __builtin_amdgcn_mfma_f32_32x32x16_bf16(w2a.v, hA0.v, acc2A.v, 0, 0, 0);
            acc2B.v = __builtin_amdgcn_mfma_f32_32x32x16_bf16(w2a.v, hB0.v, acc2B.v, 0, 0, 0);
            acc2A.v = __builtin_amdgcn_mfma_f32_32x32x16_bf16(w2b.v, hA1.v, acc2A.v, 0, 0, 0);
            acc2B.v = __builtin_amdgcn_mfma_f32_32x32x16_bf16(w2b.v, hB1.v, acc2B.v, 0, 0, 0);
            // ---- relu+pack, layer-3 dot on MFMA (C-in = b3 splat)
            PK8 gA0, gA1, gB0, gB1;
            #pragma unroll
            for (int j = 0; j < 4; ++j) {
                gA0.u[j] = pkbf(relu(acc2A.v[2 * j]),     relu(acc2A.v[2 * j + 1]));
                gA1.u[j] = pkbf(relu(acc2A.v[8 + 2 * j]), relu(acc2A.v[9 + 2 * j]));
                gB0.u[j] = pkbf(relu(acc2B.v[2 * j]),     relu(acc2B.v[2 * j + 1]));
                gB1.u[j] = pkbf(relu(acc2B.v[8 + 2 * j]), relu(acc2B.v[9 + 2 * j]));
            }
            F16Q acc3A, acc3B;
            acc3A.q[0] = tq[14 * 64 + lane]; acc3A.q[1] = tq[15 * 64 + lane];
            acc3A.q[2] = tq[16 * 64 + lane]; acc3A.q[3] = tq[17 * 64 + lane];
            acc3B = acc3A;
            acc3A.v = __builtin_amdgcn_mfma_f32_32x32x16_bf16(w3a.v, gA0.v, acc3A.v, 0, 0, 0);
            acc3B.v = __builtin_amdgcn_mfma_f32_32x32x16_bf16(w3a.v, gB0.v, acc3B.v, 0, 0, 0);
            acc3A.v = __builtin_amdgcn_mfma_f32_32x32x16_bf16(w3b.v, gA1.v, acc3A.v, 0, 0, 0);
            acc3B.v = __builtin_amdgcn_mfma_f32_32x32x16_bf16(w3b.v, gB1.v, acc3B.v, 0, 0, 0);
            // ---- sigmoid + store
            float oA = 1.f / (1.f + __expf(-acc3A.v[0]));
            float oB = 1.f / (1.f + __expf(-acc3B.v[0]));
            if (valid) { op[0] = oA; op[NI] = oB; }
            op += 2 * NI;
        }
    } else {
        // ---- user_sim (float4 dot); reuse tabf[0..63] as the row cache
        int b = bx - 2504;
        if (t < D) tabf[t] = ws[WS_N + b * D + t];
        __syncthreads();
        const float4* nj = (const float4*)(ws + WS_N + t * D);
        float acc = 0.f;
        #pragma unroll
        for (int d4 = 0; d4 < 16; ++d4) {
            float4 v = nj[d4];
            acc += tabf[4*d4+0] * v.x + tabf[4*d4+1] * v.y
                 + tabf[4*d4+2] * v.z + tabf[4*d4+3] * v.w;
        }
        out[OUT_SIM + (long)b * 256 + t] = (1.f - acc) * 0.5f;
    }
}

extern "C" void kernel_launch(void* const* d_in, const int* in_sizes, int n_in,
                              void* d_out, int out_size, void* d_ws, size_t ws_size,
                              hipStream_t stream) {
    const int*   users = (const int*)d_in[0];
    const float* uemb  = (const float*)d_in[1];
    const float* iemb  = (const float*)d_in[2];
    const float *lw0 = (const float*)d_in[3],  *lb0 = (const float*)d_in[4];
    const float *lw1 = (const float*)d_in[5],  *lb1 = (const float*)d_in[6];
    const float *lw2 = (const float*)d_in[7],  *lb2 = (const float*)d_in[8];
    const float *lw3 = (const float*)d_in[9],  *lb3 = (const float*)d_in[10];
    const float *rw0 = (const float*)d_in[11], *rb0 = (const float*)d_in[12];
    const float *rw1 = (const float*)d_in[13], *rb1 = (const float*)d_in[14];
    const float *rw2 = (const float*)d_in[15], *rb2 = (const float*)d_in[16];
    const float *rw3 = (const float*)d_in[17], *rb3 = (const float*)d_in[18];
    const float *pw0 = (const float*)d_in[19], *pb0 = (const float*)d_in[20];
    const float *pw1 = (const float*)d_in[21], *pb1 = (const float*)d_in[22];
    const float *pw2 = (const float*)d_in[23], *pb2 = (const float*)d_in[24];
    const float *pw3 = (const float*)d_in[25], *pb3 = (const float*)d_in[26];
    float* ws = (float*)d_ws;
    float* out = (float*)d_out;

    k_prep<<<1394, 256, 0, stream>>>(users, uemb, iemb,
                                     lw0, lb0, rw0, rb0,
                                     lw1, lb1, lw2, lb2, lw3, lb3,
                                     rw1, rb1, rw2, rb2, rw3, rb3,
                                     pw0, pb0, pw1, pb1, pw2, pb2, pw3, pb3,
                                     ws, out);
    k_main<<<2760, 256, 0, stream>>>(ws, out);
}